// Round 17
// baseline (313.681 us; speedup 1.0000x reference)
//
#include <hip/hip_runtime.h>
#include <math.h>

#define S 2048
#define DIM 1024
#define H 16
#define G 4
#define HPG 4
#define DK 64
#define DV 64
#define NCMP 127
#define JBLK 32
#define NSEL 16
#define WWIN 512
#define GH 32
#define SCL2 0.18033688011112042f  // 0.125 * log2(e)

typedef __attribute__((ext_vector_type(8))) __bf16 bf16x8;
typedef __attribute__((ext_vector_type(4))) float f32x4;

__device__ __forceinline__ unsigned short f2bf(float f) {
  unsigned u = __float_as_uint(f);
  unsigned r = (u + 0x7FFFu + ((u >> 16) & 1u)) >> 16;
  return (unsigned short)r;
}

__device__ __forceinline__ unsigned short f2bf_hw(float f) {
  __bf16 b = (__bf16)f;
  return *(unsigned short*)&b;
}

__device__ __forceinline__ float bf2f(unsigned short u) {
  return __uint_as_float((unsigned)u << 16);
}

__device__ __forceinline__ f32x4 mfma16(bf16x8 a, bf16x8 b, f32x4 c) {
  return __builtin_amdgcn_mfma_f32_16x16x32_bf16(a, b, c, 0, 0, 0);
}

// ---------------- fused prologue: rope_table + x->bf16 + weight transposes ----
__global__ __launch_bounds__(256) void prep(
    const float* __restrict__ x, const float* __restrict__ W0,
    const float* __restrict__ W1, const float* __restrict__ W2,
    const float* __restrict__ W3, const float* __restrict__ W4,
    const float* __restrict__ W_out, float* __restrict__ cosT,
    float* __restrict__ sinT, unsigned short* __restrict__ xb,
    unsigned short* __restrict__ Wt, unsigned short* __restrict__ WtO) {
  __shared__ float t[64 * 65];
  int bid = blockIdx.x, tid = threadIdx.x;
  if (bid < 256) {  // rope table: S*32 = 65536 = 256*256
    int idx = bid * 256 + tid;
    int s = idx >> 5, i = idx & 31;
    double inv = pow(10000.0, -2.0 * (double)i / 64.0);
    double ang = (double)s * inv;
    cosT[idx] = (float)cos(ang);
    sinT[idx] = (float)sin(ang);
  } else if (bid < 1280) {  // fconv: x -> bf16, 1024 blocks
    int idx = ((bid - 256) * 256 + tid) * 8;
    float4 a = *(const float4*)&x[idx];
    float4 b = *(const float4*)&x[idx + 4];
    union { unsigned short us[8]; float4 f4; } u;
    u.us[0] = f2bf(a.x); u.us[1] = f2bf(a.y); u.us[2] = f2bf(a.z); u.us[3] = f2bf(a.w);
    u.us[4] = f2bf(b.x); u.us[5] = f2bf(b.y); u.us[6] = f2bf(b.z); u.us[7] = f2bf(b.w);
    *(float4*)&xb[idx] = u.f4;
  } else if (bid < 1600) {  // wtrans: 5 mats x 16 k0 x 4 n0 = 320 blocks
    int p = bid - 1280;
    int m = p / 64;
    int rem = p % 64;
    int k0 = (rem & 15) * 64;
    int n0 = (rem >> 4) * 64;
    const float* W = (m == 0) ? W0 : (m == 1) ? W1 : (m == 2) ? W2 : (m == 3) ? W3 : W4;
    int rr = tid >> 4, c4 = (tid & 15) * 4;
#pragma unroll
    for (int e = 0; e < 4; ++e) {
      int row = rr + e * 16;
      float4 v = *(const float4*)(W + (size_t)(k0 + row) * 256 + n0 + c4);
      t[(c4 + 0) * 65 + row] = v.x;
      t[(c4 + 1) * 65 + row] = v.y;
      t[(c4 + 2) * 65 + row] = v.z;
      t[(c4 + 3) * 65 + row] = v.w;
    }
    __syncthreads();
#pragma unroll
    for (int e = 0; e < 2; ++e) {
      int flat = tid + e * 256;
      int col = flat >> 3, kc = (flat & 7) * 8;
      union { unsigned short us[8]; float4 f4; } u;
#pragma unroll
      for (int i = 0; i < 8; ++i) u.us[i] = f2bf(t[col * 65 + kc + i]);
      *(float4*)(Wt + ((size_t)m * 256 + n0 + col) * 1024 + k0 + kc) = u.f4;
    }
  } else {  // wtrans_o: 16 x 16 = 256 blocks
    int p = bid - 1600;
    int k0 = (p & 15) * 64;
    int n0 = (p >> 4) * 64;
    int rr = tid >> 4, c4 = (tid & 15) * 4;
#pragma unroll
    for (int e = 0; e < 4; ++e) {
      int row = rr + e * 16;
      float4 v = *(const float4*)(W_out + (size_t)(k0 + row) * 1024 + n0 + c4);
      t[(c4 + 0) * 65 + row] = v.x;
      t[(c4 + 1) * 65 + row] = v.y;
      t[(c4 + 2) * 65 + row] = v.z;
      t[(c4 + 3) * 65 + row] = v.w;
    }
    __syncthreads();
#pragma unroll
    for (int e = 0; e < 2; ++e) {
      int flat = tid + e * 256;
      int col = flat >> 3, kc = (flat & 7) * 8;
      union { unsigned short us[8]; float4 f4; } u;
#pragma unroll
      for (int i = 0; i < 8; ++i) u.us[i] = f2bf(t[col * 65 + kc + i]);
      *(float4*)(WtO + (size_t)(n0 + col) * 1024 + k0 + kc) = u.f4;
    }
  }
}

// ---------------- fp32 GEMM body: 64x64 tile, K-step 32 (proven) --------------
__device__ __forceinline__ void gemm_body_k(const float* __restrict__ A,
                                            const float* __restrict__ B,
                                            float* __restrict__ C,
                                            int N, int K, int bm, int bn,
                                            int kS, int kE,
                                            float* As /*32*64*/, float* Bs /*32*64*/) {
  int tid = threadIdx.x;
  int tr = tid >> 4, tc = tid & 15;
  float acc[4][4] = {{0.f}};
  int arow = tid >> 2;
  int kba = (tid & 3) << 3;
  int brow = tid >> 4;
  int bcol = (tid & 15) << 2;
  const float* Ab = A + (size_t)(bm * 64) * K;
  const float* Bb = B + bn * 64;

  float4 a0 = *(const float4*)(Ab + (size_t)arow * K + kS + kba);
  float4 a1 = *(const float4*)(Ab + (size_t)arow * K + kS + kba + 4);
  float4 b0 = *(const float4*)(Bb + (size_t)(kS + brow) * N + bcol);
  float4 b1 = *(const float4*)(Bb + (size_t)(kS + brow + 16) * N + bcol);

  for (int k0 = kS; k0 < kE; k0 += 32) {
    __syncthreads();
    {
      float av[8] = {a0.x, a0.y, a0.z, a0.w, a1.x, a1.y, a1.z, a1.w};
#pragma unroll
      for (int i = 0; i < 8; ++i) {
        int k = kba + i;
        As[k * 64 + (arow ^ (((k >> 3) & 3) << 3))] = av[i];
      }
      *(float4*)&Bs[brow * 64 + bcol] = b0;
      *(float4*)&Bs[(brow + 16) * 64 + bcol] = b1;
    }
    __syncthreads();
    if (k0 + 32 < kE) {
      a0 = *(const float4*)(Ab + (size_t)arow * K + k0 + 32 + kba);
      a1 = *(const float4*)(Ab + (size_t)arow * K + k0 + 32 + kba + 4);
      b0 = *(const float4*)(Bb + (size_t)(k0 + 32 + brow) * N + bcol);
      b1 = *(const float4*)(Bb + (size_t)(k0 + 32 + brow + 16) * N + bcol);
    }
#pragma unroll
    for (int kk = 0; kk < 32; ++kk) {
      float4 a = *(const float4*)&As[kk * 64 + ((tr << 2) ^ (((kk >> 3) & 3) << 3))];
      float4 b = *(const float4*)&Bs[kk * 64 + (tc << 2)];
      acc[0][0] += a.x * b.x; acc[0][1] += a.x * b.y; acc[0][2] += a.x * b.z; acc[0][3] += a.x * b.w;
      acc[1][0] += a.y * b.x; acc[1][1] += a.y * b.y; acc[1][2] += a.y * b.z; acc[1][3] += a.y * b.w;
      acc[2][0] += a.z * b.x; acc[2][1] += a.z * b.y; acc[2][2] += a.z * b.z; acc[2][3] += a.z * b.w;
      acc[3][0] += a.w * b.x; acc[3][1] += a.w * b.y; acc[3][2] += a.w * b.z; acc[3][3] += a.w * b.w;
    }
  }
  for (int i = 0; i < 4; ++i)
    for (int jj = 0; jj < 4; ++jj)
      C[(size_t)(bm * 64 + (tr << 2) + i) * N + bn * 64 + (tc << 2) + jj] = acc[i][jj];
}

// ---------------- bf16 MFMA projection body -----------------------------------
__device__ __forceinline__ void proj_body(
    const unsigned short* __restrict__ xb, const unsigned short* __restrict__ Wt,
    const float* __restrict__ cosT, const float* __restrict__ sinT,
    unsigned short* __restrict__ Kb_s, unsigned short* __restrict__ Vt_s,
    unsigned short* __restrict__ Kb_w, unsigned short* __restrict__ Vt_w,
    unsigned short* __restrict__ Vt_c,
    int s0, int g, int mat, unsigned short* xs, unsigned short* ws) {
  int tid = threadIdx.x, w = tid >> 6, lane = tid & 63;
  int l15 = lane & 15, lg = lane >> 4;
  int rswz = (l15 & 7) << 3;
  bool isV = (mat == 1) || (mat == 3) || (mat == 4);
  const unsigned short* wt = Wt + ((size_t)mat * 256 + g * 64) * 1024;

  f32x4 acc[4];
#pragma unroll
  for (int nt = 0; nt < 4; ++nt) acc[nt] = (f32x4){0.f, 0.f, 0.f, 0.f};

  for (int k0 = 0; k0 < DIM; k0 += 64) {
#pragma unroll
    for (int e = 0; e < 2; ++e) {
      int flat = tid + e * 256;
      int row = flat >> 3, cc = flat & 7;
      int dsti = row * 64 + ((cc ^ (row & 7)) << 3);
      *(float4*)&xs[dsti] = *(const float4*)(xb + (size_t)(s0 + row) * DIM + k0 + cc * 8);
      *(float4*)&ws[dsti] = *(const float4*)(wt + (size_t)row * DIM + k0 + cc * 8);
    }
    __syncthreads();
    const unsigned short* aP = isV ? ws : xs;
    const unsigned short* bP = isV ? xs : ws;
    int arow = w * 16 + l15;
    bf16x8 af[2];
#pragma unroll
    for (int kc = 0; kc < 2; ++kc)
      af[kc] = *(const bf16x8*)&aP[(arow * 64 + kc * 32 + lg * 8) ^ rswz];
#pragma unroll
    for (int nt = 0; nt < 4; ++nt) {
      int brow = nt * 16 + l15;
      bf16x8 b0 = *(const bf16x8*)&bP[(brow * 64 + lg * 8) ^ rswz];
      bf16x8 b1 = *(const bf16x8*)&bP[(brow * 64 + 32 + lg * 8) ^ rswz];
      acc[nt] = mfma16(af[0], b0, acc[nt]);
      acc[nt] = mfma16(af[1], b1, acc[nt]);
    }
    __syncthreads();
  }

  if (!isV) {
    unsigned short* Kb = (mat == 0) ? Kb_s : Kb_w;
#pragma unroll
    for (int rr = 0; rr < 4; ++rr) {
      int tok = s0 + w * 16 + lg * 4 + rr;
#pragma unroll
      for (int p = 0; p < 2; ++p) {
        int i = p * 16 + l15;
        float c = cosT[tok * 32 + i], sn = sinT[tok * 32 + i];
        float x1 = acc[p][rr], x2 = acc[p + 2][rr];
        Kb[((size_t)g * S + tok) * 64 + i] = f2bf(x1 * c - x2 * sn);
        Kb[((size_t)g * S + tok) * 64 + i + 32] = f2bf(x2 * c + x1 * sn);
      }
    }
  } else {
    unsigned short* Vt = (mat == 1) ? Vt_s : (mat == 3) ? Vt_w : Vt_c;
#pragma unroll
    for (int rr = 0; rr < 4; ++rr) {
      int col = w * 16 + lg * 4 + rr;
#pragma unroll
      for (int nt = 0; nt < 4; ++nt) {
        int tok = s0 + nt * 16 + l15;
        Vt[((size_t)g * 64 + col) * S + tok] = f2bf(acc[nt][rr]);
      }
    }
  }
}

// ---------------- Superkernel: fp32 Q/K_cmp GEMM (VALU) + bf16 proj (MFMA) ----
__global__ __launch_bounds__(256) void qk_proj(
    const float* __restrict__ x, const float* __restrict__ W_Q,
    const float* __restrict__ W_Kc, float* __restrict__ Pq, float* __restrict__ Pk,
    const unsigned short* __restrict__ xb, const unsigned short* __restrict__ Wt,
    const float* __restrict__ cosT, const float* __restrict__ sinT,
    unsigned short* __restrict__ Kb_s, unsigned short* __restrict__ Vt_s,
    unsigned short* __restrict__ Kb_w, unsigned short* __restrict__ Vt_w,
    unsigned short* __restrict__ Vt_c) {
  __shared__ __align__(16) float lds_f[4096];
  int bid = blockIdx.x;
  int r = bid % 3;
  if (r < 2) {
    int gid = (bid / 3) * 2 + r;
    int z = gid / 640;
    int rem = gid % 640;
    int ct = rem % 20;
    int bm = rem / 20;
    int kS = z * 512, kE = kS + 512;
    float* As = lds_f;
    float* Bs = lds_f + 2048;
    if (ct < 16)
      gemm_body_k(x, W_Q, Pq + (size_t)z * S * 1024, 1024, DIM, bm, ct, kS, kE, As, Bs);
    else
      gemm_body_k(x, W_Kc, Pk + (size_t)z * S * 256, 256, DIM, bm, ct - 16, kS, kE, As, Bs);
  } else {
    int pid = bid / 3;
    int s0b = pid % 32;
    int g = (pid / 32) % 4;
    int mat = pid / 128;
    unsigned short* xs = (unsigned short*)lds_f;
    unsigned short* ws = xs + 4096;
    proj_body(xb, Wt, cosT, sinT, Kb_s, Vt_s, Kb_w, Vt_w, Vt_c, s0b * 64, g, mat,
              xs, ws);
  }
}

// ---------------- reduce split-K partials + RoPE + bf16 Q ---------------------
__global__ __launch_bounds__(256) void reduce_rope(
    const float* __restrict__ Pq, const float* __restrict__ Pk,
    const float* __restrict__ cosT, const float* __restrict__ sinT,
    float* __restrict__ Qb, unsigned short* __restrict__ Qbf,
    float* __restrict__ Kcr) {
  int idx = blockIdx.x * 256 + threadIdx.x;
  const int NQ = S * H * 32;
  if (idx < NQ) {
    int i = idx & 31;
    int rest = idx >> 5;
    int h = rest & 15;
    int s = rest >> 4;
    size_t base = (size_t)s * 1024 + h * 64 + i;
    float a1 = Pq[base] + Pq[(size_t)S * 1024 + base];
    float a2 = Pq[base + 32] + Pq[(size_t)S * 1024 + base + 32];
    float c = cosT[s * 32 + i], sn = sinT[s * 32 + i];
    float q1 = a1 * c - a2 * sn, q2 = a2 * c + a1 * sn;
    Qb[base] = q1;
    Qb[base + 32] = q2;
    Qbf[base] = f2bf(q1);
    Qbf[base + 32] = f2bf(q2);
  } else {
    int j = idx - NQ;
    if (j >= S * G * 32) return;
    int i = j & 31;
    int rest = j >> 5;
    int g = rest & 3;
    int s = rest >> 2;
    size_t base = (size_t)s * 256 + g * 64 + i;
    float a1 = Pk[base] + Pk[(size_t)S * 256 + base];
    float a2 = Pk[base + 32] + Pk[(size_t)S * 256 + base + 32];
    float c = cosT[s * 32 + i], sn = sinT[s * 32 + i];
    Kcr[base] = a1 * c - a2 * sn;
    Kcr[base + 32] = a2 * c + a1 * sn;
  }
}

// ---------------- fused pool_cmp + gating MLP ---------------------------------
__global__ __launch_bounds__(256) void post_reduce(
    const float* __restrict__ Kcr, const unsigned short* __restrict__ Vtc,
    float* __restrict__ Kc, float* __restrict__ Vc, const float* __restrict__ Q,
    const float* __restrict__ w1, const float* __restrict__ b1,
    const float* __restrict__ w2, const float* __restrict__ b2,
    float* __restrict__ gates) {
  int bid = blockIdx.x, tid = threadIdx.x;
  if (bid < 127) {
    int item = bid * 256 + tid;
    int c = item >> 8;
    int g = (item >> 6) & 3;
    int d = item & 63;
    float sk = 0.f, sv = 0.f;
    const unsigned short* vrow = Vtc + ((size_t)g * 64 + d) * S + c * 16;
    for (int l = 0; l < 32; ++l) {
      sk += Kcr[(size_t)((c * 16 + l) * G + g) * 64 + d];
      sv += bf2f(vrow[l]);
    }
    Kc[(size_t)(g * NCMP + c) * 64 + d] = sk * (1.f / 32.f);
    Vc[(size_t)(g * NCMP + c) * 64 + d] = sv * (1.f / 32.f);
  } else {
    int idx = (bid - 127) * 256 + tid;
    int s = idx >> 2, g = idx & 3;
    float qm[64];
#pragma unroll
    for (int d = 0; d < 64; ++d) {
      float a = 0.f;
      for (int hp = 0; hp < HPG; ++hp) a += Q[(size_t)(s * H + g * HPG + hp) * 64 + d];
      qm[d] = a * 0.25f;
    }
    float gl[3] = {b2[0], b2[1], b2[2]};
    for (int j = 0; j < GH; ++j) {
      float z = b1[j];
      for (int d = 0; d < 64; ++d) z += qm[d] * w1[d * GH + j];
      float sl = z / (1.f + expf(-z));
      gl[0] += sl * w2[j * 3 + 0];
      gl[1] += sl * w2[j * 3 + 1];
      gl[2] += sl * w2[j * 3 + 2];
    }
    float m = fmaxf(gl[0], fmaxf(gl[1], gl[2]));
    float e0 = expf(gl[0] - m), e1 = expf(gl[1] - m), e2 = expf(gl[2] - m);
    float inv = 1.f / (e0 + e1 + e2);
    float p0 = e0 * inv, p1 = e1 * inv, p2 = e2 * inv;
    int am = (gl[0] >= gl[1] && gl[0] >= gl[2]) ? 0 : ((gl[1] >= gl[2]) ? 1 : 2);
    float t1 = (am == 0) ? fmaxf(gl[1], gl[2])
                         : ((am == 1) ? fmaxf(gl[0], gl[2]) : fmaxf(gl[0], gl[1]));
    if (m - t1 > 50.f) {
      p0 = (am == 0) ? 1.f : 0.f;
      p1 = (am == 1) ? 1.f : 0.f;
      p2 = (am == 2) ? 1.f : 0.f;
    }
    gates[idx * 3 + 0] = p0;
    gates[idx * 3 + 1] = p1;
    gates[idx * 3 + 2] = p2;
  }
}

// ---------------- compressed attention + top-k body (fp32 exact) --------------
__device__ __forceinline__ void cmp_body(const float* __restrict__ Q,
                                         const float* __restrict__ Kc,
                                         const float* __restrict__ Vc,
                                         float* __restrict__ Ocmp,
                                         unsigned int* __restrict__ selm,
                                         int s, int g,
                                         float* q4, float* sc, float* pg) {
  int tid = threadIdx.x;
  int nvis = (s >= 31) ? (((s - 31) >> 4) + 1) : 0;
  {
    int h = tid >> 6, d = tid & 63;
    q4[h * 64 + d] = Q[(size_t)(s * H + g * HPG + h) * 64 + d];
  }
  __syncthreads();

  if (tid < 128) {
    int c = tid;
    if (c < nvis) {
      float a0 = 0.f, a1 = 0.f, a2 = 0.f, a3 = 0.f;
      const float* kr = &Kc[(size_t)(g * NCMP + c) * 64];
#pragma unroll 4
      for (int kk = 0; kk < 16; ++kk) {
        float4 kv = *(const float4*)&kr[kk * 4];
        float4 q0 = *(const float4*)&q4[0 * 64 + kk * 4];
        float4 q1 = *(const float4*)&q4[1 * 64 + kk * 4];
        float4 q2 = *(const float4*)&q4[2 * 64 + kk * 4];
        float4 q3 = *(const float4*)&q4[3 * 64 + kk * 4];
        a0 += q0.x * kv.x + q0.y * kv.y + q0.z * kv.z + q0.w * kv.w;
        a1 += q1.x * kv.x + q1.y * kv.y + q1.z * kv.z + q1.w * kv.w;
        a2 += q2.x * kv.x + q2.y * kv.y + q2.z * kv.z + q2.w * kv.w;
        a3 += q3.x * kv.x + q3.y * kv.y + q3.z * kv.z + q3.w * kv.w;
      }
      sc[0 * 128 + c] = a0 * 0.125f;
      sc[1 * 128 + c] = a1 * 0.125f;
      sc[2 * 128 + c] = a2 * 0.125f;
      sc[3 * 128 + c] = a3 * 0.125f;
    } else {
      sc[0 * 128 + c] = -INFINITY;
      sc[1 * 128 + c] = -INFINITY;
      sc[2 * 128 + c] = -INFINITY;
      sc[3 * 128 + c] = -INFINITY;
    }
  }
  __syncthreads();

  int w = tid >> 6, lane = tid & 63;
  {
    float v0 = sc[w * 128 + lane];
    float v1 = (lane + 64 < NCMP) ? sc[w * 128 + lane + 64] : -INFINITY;
    float m = fmaxf(v0, v1);
    for (int off = 32; off; off >>= 1) m = fmaxf(m, __shfl_xor(m, off));
    float e0 = (m > -INFINITY && v0 > -INFINITY) ? expf(v0 - m) : 0.f;
    float e1 = (m > -INFINITY && v1 > -INFINITY) ? expf(v1 - m) : 0.f;
    float sum = e0 + e1;
    for (int off = 32; off; off >>= 1) sum += __shfl_xor(sum, off);
    float inv = (sum > 0.f) ? 1.f / sum : 0.f;
    sc[w * 128 + lane] = e0 * inv;
    if (lane + 64 < NCMP) sc[w * 128 + lane + 64] = e1 * inv;
    if (lane == 63) sc[w * 128 + 127] = 0.f;
  }
  __syncthreads();

  {
    int h = tid >> 6, d = tid & 63;
    float o = 0.f;
#pragma unroll 4
    for (int c = 0; c < nvis; ++c)
      o += sc[h * 128 + c] * Vc[(size_t)(g * NCMP + c) * 64 + d];
    Ocmp[(size_t)(s * H + g * HPG + h) * 64 + d] = o;
  }

  if (tid < JBLK) {
    int j = tid;
    float a = 0.f;
#pragma unroll
    for (int h = 0; h < 4; ++h) {
      const float* row = &sc[h * 128];
      float v = row[4 * j] + row[4 * j + 1] + row[4 * j + 2] + 0.5f * row[4 * j + 3];
      if (j > 0) v += 0.5f * row[4 * j - 1];
      a += v;
    }
    pg[j] = a;
  }
  __syncthreads();

  if (tid < 64) {
    int j = tid & 31;
    int cur = s >> 6;
    float v = (j * 64 <= s) ? pg[j] : -1e30f;
    if (j == 0 || j == cur) v = 1e9f;
    unsigned int mask = 0;
#pragma unroll 1
    for (int n = 0; n < NSEL; ++n) {
      float bv = v;
      int bj = j;
#pragma unroll
      for (int off = 1; off < 32; off <<= 1) {
        float ov = __shfl_xor(bv, off);
        int oj = __shfl_xor(bj, off);
        if (ov > bv || (ov == bv && oj < bj)) { bv = ov; bj = oj; }
      }
      mask |= 1u << bj;
      if (j == bj) v = -INFINITY;
    }
    if (tid == 0) selm[(size_t)s * G + g] = mask;
  }
}

// ---------------- MFMA flash attention body: MODE 0 sel / 1 win ---------------
// Pl ALIASES Kl (Kl is dead after the QK MFMAs; a barrier separates the last
// Kl read from the first Pl write). LDS: Kl/Pl 8KB + Vt 8KB.
template <int MODE>
__device__ __forceinline__ void attn_body(
    const unsigned short* __restrict__ Qbf, const unsigned short* __restrict__ Kb,
    const unsigned short* __restrict__ Vtb, const unsigned int* __restrict__ selm,
    float* __restrict__ O, int t0, int g,
    unsigned short* Kl, unsigned short* Vt,
    unsigned int* sel_l, int* blist, int* nB_p) {
  int tid = threadIdx.x;
  int w = tid >> 6, lane = tid & 63;
  int l15 = lane & 15, lg = lane >> 4;
  int rswz = (l15 & 7) << 3;
  int jdiag = t0 >> 6;
  unsigned short* Pl = Kl;  // alias: Kl dead after QK MFMAs

  if (MODE == 0 && tid < 16) sel_l[tid] = selm[(t0 + tid) * G + g];
  __syncthreads();
  if (tid == 0) {
    int n = 0;
    if (MODE == 0) {
      unsigned int un = 0;
      for (int i = 0; i < 16; ++i) un |= sel_l[i];
      for (int j = 0; j <= jdiag; ++j)
        if ((un >> j) & 1u) blist[n++] = j;
    } else {
      int lo = t0 - (WWIN - 1);
      int j0 = (lo > 0) ? (lo >> 6) : 0;
      for (int j = j0; j <= jdiag; ++j) blist[n++] = j;
    }
    *nB_p = n;
  }
  __syncthreads();
  int nB = *nB_p;

  int tok = t0 + l15;
  bf16x8 qf[2];
  {
    const unsigned short* qb = Qbf + ((size_t)tok * H + g * HPG + w) * 64;
    qf[0] = *(const bf16x8*)(qb + lg * 8);
    qf[1] = *(const bf16x8*)(qb + 32 + lg * 8);
  }

  float mrun = -INFINITY, lrun = 0.f;
  f32x4 oacc[4];
#pragma unroll
  for (int dt = 0; dt < 4; ++dt) oacc[dt] = (f32x4){0.f, 0.f, 0.f, 0.f};

  for (int b = 0; b < nB; ++b) {
    int j = blist[b];
    int ku = j * 64;

    {
      const unsigned short* src = Kb + ((size_t)g * S + ku) * 64;
#pragma unroll
      for (int c2 = 0; c2 < 2; ++c2) {
        int chunk = tid + c2 * 256;
        int key = chunk >> 3, cc = chunk & 7;
        *(float4*)&Kl[key * 64 + ((cc ^ (key & 7)) << 3)] =
            *(const float4*)(src + chunk * 8);
      }
#pragma unroll
      for (int c2 = 0; c2 < 2; ++c2) {
        int chunk = tid + c2 * 256;
        int dim = chunk >> 3, cc = chunk & 7;
        *(float4*)&Vt[dim * 64 + ((cc ^ (dim & 7)) << 3)] =
            *(const float4*)(Vtb + ((size_t)g * 64 + dim) * S + ku + cc * 8);
      }
    }
    __syncthreads();

    f32x4 sf[4];
#pragma unroll
    for (int kt = 0; kt < 4; ++kt) sf[kt] = (f32x4){0.f, 0.f, 0.f, 0.f};
#pragma unroll
    for (int kt = 0; kt < 4; ++kt) {
      int krow = kt * 16 + l15;
      bf16x8 kf0 = *(const bf16x8*)&Kl[(krow * 64 + lg * 8) ^ rswz];
      bf16x8 kf1 = *(const bf16x8*)&Kl[(krow * 64 + 32 + lg * 8) ^ rswz];
      sf[kt] = mfma16(kf0, qf[0], sf[kt]);
      sf[kt] = mfma16(kf1, qf[1], sf[kt]);
    }
    __syncthreads();  // all waves done reading Kl (Pl aliases it)

    bool bsel = true;
    if (MODE == 0) bsel = ((sel_l[l15] >> j) & 1u) != 0;
    float sv2[4][4];
    if (j == jdiag) {
#pragma unroll
      for (int kt = 0; kt < 4; ++kt)
#pragma unroll
        for (int rr = 0; rr < 4; ++rr) {
          int u = ku + kt * 16 + lg * 4 + rr;
          sv2[kt][rr] = (u <= tok) ? sf[kt][rr] * SCL2 : -INFINITY;
        }
    } else if (MODE == 1 && (ku + WWIN <= t0 + 15)) {
#pragma unroll
      for (int kt = 0; kt < 4; ++kt)
#pragma unroll
        for (int rr = 0; rr < 4; ++rr) {
          int u = ku + kt * 16 + lg * 4 + rr;
          sv2[kt][rr] = (u + WWIN > tok) ? sf[kt][rr] * SCL2 : -INFINITY;
        }
    } else {
#pragma unroll
      for (int kt = 0; kt < 4; ++kt)
#pragma unroll
        for (int rr = 0; rr < 4; ++rr) sv2[kt][rr] = sf[kt][rr] * SCL2;
    }

    float pmax = -INFINITY;
#pragma unroll
    for (int kt = 0; kt < 4; ++kt)
#pragma unroll
      for (int rr = 0; rr < 4; ++rr) pmax = fmaxf(pmax, sv2[kt][rr]);
    pmax = fmaxf(pmax, __shfl_xor(pmax, 16));
    pmax = fmaxf(pmax, __shfl_xor(pmax, 32));
    if (MODE == 0 && !bsel) pmax = -INFINITY;

    if (__any(pmax > mrun)) {
      float mnew = fmaxf(mrun, pmax);
      float mc = (mnew == -INFINITY) ? 0.f : mnew;
      float fac = exp2f(mrun - mc);
      mrun = mnew;
      lrun *= fac;
#pragma unroll
      for (int dt = 0; dt < 4; ++dt)
#pragma unroll
        for (int rr = 0; rr < 4; ++rr) oacc[dt][rr] *= fac;
    }
    float mcb = (MODE == 0 && !bsel) ? INFINITY
                                     : ((mrun == -INFINITY) ? 0.f : mrun);

    float psum = 0.f;
    unsigned short pb[16];
#pragma unroll
    for (int kt = 0; kt < 4; ++kt)
#pragma unroll
      for (int rr = 0; rr < 4; ++rr) {
        float e = exp2f(sv2[kt][rr] - mcb);
        psum += e;
        pb[kt * 4 + rr] = f2bf_hw(e);
      }
    psum += __shfl_xor(psum, 16);
    psum += __shfl_xor(psum, 32);
    lrun += psum;

    {
      unsigned short* pw = Pl + w * 1024;  // per-wave slice, no cross-wave hazard
#pragma unroll
      for (int kt = 0; kt < 4; ++kt) {
        int idx = (l15 * 64 + kt * 16 + lg * 4) ^ rswz;
        unsigned int lo = (unsigned)pb[kt * 4] | ((unsigned)pb[kt * 4 + 1] << 16);
        unsigned int hi = (unsigned)pb[kt * 4 + 2] | ((unsigned)pb[kt * 4 + 3] << 16);
        *(uint2*)&pw[idx] = make_uint2(lo, hi);
      }
    }

#pragma unroll
    for (int kc = 0; kc < 2; ++kc) {
      bf16x8 pf = *(const bf16x8*)&Pl[w * 1024 + ((l15 * 64 + kc * 32 + lg * 8) ^ rswz)];
#pragma unroll
      for (int dt = 0; dt < 4; ++dt) {
        bf16x8 vf = *(const bf16x8*)&Vt[((dt * 16 + l15) * 64 + kc * 32 + lg * 8) ^ rswz];
        oacc[dt] = mfma16(vf, pf, oacc[dt]);
      }
    }
    __syncthreads();  // Pl/Vt reads complete before next restage
  }

  {
    float inv = (lrun > 0.f) ? 1.f / lrun : 0.f;
    float* ob = O + ((size_t)tok * H + g * HPG + w) * 64;
#pragma unroll
    for (int dt = 0; dt < 4; ++dt) {
      float4 v;
      v.x = oacc[dt][0] * inv;
      v.y = oacc[dt][1] * inv;
      v.z = oacc[dt][2] * inv;
      v.w = oacc[dt][3] * inv;
      *(float4*)(ob + dt * 16 + lg * 4) = v;
    }
  }
}

// ---------------- Superkernel: cmp_attn (VALU) + win attention (MFMA) ---------
// 8704 blocks, striped 16:1. Union LDS only 16.5 KB (Pl aliases Kl) so the
// cmp path keeps ~8 blocks/CU resident (R15's 24.5 KB killed it).
__global__ __launch_bounds__(256) void cmp_win(
    const float* __restrict__ Qb, const float* __restrict__ Kc,
    const float* __restrict__ Vc, float* __restrict__ Ocmp,
    unsigned int* __restrict__ selm, const unsigned short* __restrict__ Qbf,
    const unsigned short* __restrict__ Kbw, const unsigned short* __restrict__ Vtw,
    float* __restrict__ Owin) {
  __shared__ __align__(16) unsigned char ldsb[16768];
  int bid = blockIdx.x;
  if (bid % 17 != 16) {
    int cid = (bid / 17) * 16 + (bid % 17);  // 0..8191
    int s = cid >> 2, g = cid & 3;
    float* q4 = (float*)ldsb;
    float* sc = q4 + 256;
    float* pg = sc + 512;
    cmp_body(Qb, Kc, Vc, Ocmp, selm, s, g, q4, sc, pg);
  } else {
    int pid = bid / 17;  // 0..511
    int t0 = (pid & 127) * 16;
    int g = pid >> 7;
    unsigned short* Kl = (unsigned short*)ldsb;  // 4096 (Pl aliases)
    unsigned short* Vt = Kl + 4096;              // 4096
    int* blist = (int*)(Vt + 4096);
    int* nB_p = blist + JBLK;
    attn_body<1>(Qbf, Kbw, Vtw, nullptr, Owin, t0, g, Kl, Vt, nullptr, blist,
                 nB_p);
  }
}

// ---------------- sel attention (needs selm -> runs after cmp_win) ------------
__global__ __launch_bounds__(256) void attn_sel(
    const unsigned short* __restrict__ Qbf, const unsigned short* __restrict__ Kbs,
    const unsigned short* __restrict__ Vts, const unsigned int* __restrict__ selm,
    float* __restrict__ Osel) {
  __shared__ unsigned short Kl[4096];  // Pl aliases
  __shared__ unsigned short Vt[4096];
  __shared__ unsigned int sel_l[16];
  __shared__ int blist[JBLK];
  __shared__ int nB_s;
  int t0 = blockIdx.x * 16;
  int g = blockIdx.y;
  attn_body<0>(Qbf, Kbs, Vts, selm, Osel, t0, g, Kl, Vt, sel_l, blist, &nB_s);
}

// ---------------- combine branches -> bf16 ------------------------------------
__global__ void combine(const float* __restrict__ Oc, const float* __restrict__ Os,
                        const float* __restrict__ Ow, const float* __restrict__ gates,
                        unsigned short* __restrict__ Ob) {
  int idx = blockIdx.x * blockDim.x + threadIdx.x;
  if (idx >= S * H * DV) return;
  int h = (idx >> 6) & 15;
  int s = idx >> 10;
  int g = h >> 2;
  const float* gp = &gates[(size_t)(s * G + g) * 3];
  Ob[idx] = f2bf(gp[0] * Oc[idx] + gp[1] * Os[idx] + gp[2] * Ow[idx]);
}

// ---------------- bf16 MFMA out projection ------------------------------------
__global__ __launch_bounds__(256) void gemm_out(const unsigned short* __restrict__ Ob,
                                                const unsigned short* __restrict__ Wt,
                                                float* __restrict__ out) {
  __shared__ unsigned short xs[64 * 64];
  __shared__ unsigned short ws[64 * 64];
  int s0 = blockIdx.x * 64;
  int n0 = blockIdx.y * 64;
  int tid = threadIdx.x, w = tid >> 6, lane = tid & 63;
  int l15 = lane & 15, lg = lane >> 4;
  int rswz = (l15 & 7) << 3;

  f32x4 acc[4];
#pragma unroll
  for (int nt = 0; nt < 4; ++nt) acc[nt] = (f32x4){0.f, 0.f, 0.f, 0.f};

  for (int k0 = 0; k0 < DIM; k0 += 64) {
#pragma unroll
    for (int e = 0; e < 2; ++e) {
      int flat = tid + e * 256;
      int row = flat >> 3, cc = flat & 7;
      int dsti = row * 64 + ((cc ^ (row & 7)) << 3);
      *(float4*)&xs[dsti] = *(const float4*)(Ob + (size_t)(s0 + row) * DIM + k0 + cc * 8);
      *(float4*)&ws[dsti] = *(const float4*)(Wt + (size_t)(n0 + row) * DIM + k0 + cc * 8);
    }
    __syncthreads();
    int arow = w * 16 + l15;
    bf16x8 af0 = *(const bf16x8*)&xs[(arow * 64 + lg * 8) ^ rswz];
    bf16x8 af1 = *(const bf16x8*)&xs[(arow * 64 + 32 + lg * 8) ^ rswz];
#pragma unroll
    for (int nt = 0; nt < 4; ++nt) {
      int brow = nt * 16 + l15;
      bf16x8 b0 = *(const bf16x8*)&ws[(brow * 64 + lg * 8) ^ rswz];
      bf16x8 b1 = *(const bf16x8*)&ws[(brow * 64 + 32 + lg * 8) ^ rswz];
      acc[nt] = mfma16(af0, b0, acc[nt]);
      acc[nt] = mfma16(af1, b1, acc[nt]);
    }
    __syncthreads();
  }

#pragma unroll
  for (int nt = 0; nt < 4; ++nt)
#pragma unroll
    for (int rr = 0; rr < 4; ++rr)
      out[(size_t)(s0 + w * 16 + lg * 4 + rr) * 1024 + n0 + nt * 16 + l15] =
          acc[nt][rr];
}

// ---------------- host launch ---------------------------------------------------
extern "C" void kernel_launch(void* const* d_in, const int* in_sizes, int n_in,
                              void* d_out, int out_size, void* d_ws, size_t ws_size,
                              hipStream_t stream) {
  const float* x = (const float*)d_in[0];
  const float* W_Q = (const float*)d_in[1];
  const float* W_K_sel = (const float*)d_in[2];
  const float* W_V_sel = (const float*)d_in[3];
  const float* W_K_win = (const float*)d_in[4];
  const float* W_V_win = (const float*)d_in[5];
  const float* W_K_cmp = (const float*)d_in[6];
  const float* W_V_cmp = (const float*)d_in[7];
  const float* W_out = (const float*)d_in[8];
  const float* gw1 = (const float*)d_in[9];
  const float* gb1 = (const float*)d_in[10];
  const float* gw2 = (const float*)d_in[11];
  const float* gb2 = (const float*)d_in[12];

  float* w = (float*)d_ws;
  float* cosT = w;  w += S * 32;
  float* sinT = w;  w += S * 32;
  float* Qb   = w;  w += S * H * DK;
  float* Kcr  = w;  w += S * G * DK;
  float* Kc   = w;  w += G * NCMP * DK;
  float* Vc   = w;  w += G * NCMP * DV;
  float* Ocmp = w;  w += S * H * DV;   // aliased by Pq (dead until cmp_win)
  float* Osel = w;  w += S * H * DV;   // aliased by Pq tail
  float* Owin = w;  w += S * H * DV;   // aliased by Pk
  float* gates= w;  w += S * G * 3;
  unsigned int* selm = (unsigned int*)w;  w += S * G;
  unsigned short* Kbf_s = (unsigned short*)w;  w += (size_t)G * S * 64 / 2;
  unsigned short* Kbf_w = (unsigned short*)w;  w += (size_t)G * S * 64 / 2;
  unsigned short* Vt_s  = (unsigned short*)w;  w += (size_t)G * S * 64 / 2;
  unsigned short* Vt_w  = (unsigned short*)w;  w += (size_t)G * S * 64 / 2;
  unsigned short* Vt_c  = (unsigned short*)w;  w += (size_t)G * S * 64 / 2;
  unsigned short* Qbf   = (unsigned short*)w;  w += (size_t)S * H * 64 / 2;
  unsigned short* xb    = (unsigned short*)w;  w += (size_t)S * DIM / 2;
  unsigned short* Wt    = (unsigned short*)w;  w += (size_t)5 * 256 * DIM / 2;
  unsigned short* Ob    = (unsigned short*)w;  w += (size_t)S * H * DV / 2;
  unsigned short* WtO   = (unsigned short*)w;  w += (size_t)DIM * DIM / 2;

  // split-K partials alias the (not-yet-written) attention output buffers:
  float* Pq = Ocmp;
  float* Pk = Owin;

  prep<<<1856, 256, 0, stream>>>(x, W_K_sel, W_V_sel, W_K_win, W_V_win, W_V_cmp,
                                 W_out, cosT, sinT, xb, Wt, WtO);

  qk_proj<<<1920, 256, 0, stream>>>(x, W_Q, W_K_cmp, Pq, Pk, xb, Wt, cosT, sinT,
                                    Kbf_s, Vt_s, Kbf_w, Vt_w, Vt_c);
  reduce_rope<<<(S * (H + G) * 32 + 255) / 256, 256, 0, stream>>>(
      Pq, Pk, cosT, sinT, Qb, Qbf, Kcr);

  post_reduce<<<159, 256, 0, stream>>>(Kcr, Vt_c, Kc, Vc, Qb, gw1, gb1, gw2, gb2,
                                       gates);

  cmp_win<<<8704, 256, 0, stream>>>(Qb, Kc, Vc, Ocmp, selm, Qbf, Kbf_w, Vt_w, Owin);
  attn_sel<<<dim3(S / 16, G), 256, 0, stream>>>(Qbf, Kbf_s, Vt_s, selm, Osel);

  combine<<<(S * H * DV + 255) / 256, 256, 0, stream>>>(Ocmp, Osel, Owin, gates, Ob);

  gemm_out<<<dim3(S / 64, DIM / 64), 256, 0, stream>>>(Ob, WtO, (float*)d_out);
}

// Round 18
// 281.567 us; speedup vs baseline: 1.1141x; 1.1141x over previous
//
#include <hip/hip_runtime.h>
#include <math.h>

#define S 2048
#define DIM 1024
#define H 16
#define G 4
#define HPG 4
#define DK 64
#define DV 64
#define NCMP 127
#define JBLK 32
#define NSEL 16
#define WWIN 512
#define GH 32
#define SCL2 0.18033688011112042f  // 0.125 * log2(e)

typedef __attribute__((ext_vector_type(8))) __bf16 bf16x8;
typedef __attribute__((ext_vector_type(4))) float f32x4;

__device__ __forceinline__ unsigned short f2bf(float f) {
  unsigned u = __float_as_uint(f);
  unsigned r = (u + 0x7FFFu + ((u >> 16) & 1u)) >> 16;
  return (unsigned short)r;
}

__device__ __forceinline__ unsigned short f2bf_hw(float f) {
  __bf16 b = (__bf16)f;
  return *(unsigned short*)&b;
}

__device__ __forceinline__ float bf2f(unsigned short u) {
  return __uint_as_float((unsigned)u << 16);
}

__device__ __forceinline__ f32x4 mfma16(bf16x8 a, bf16x8 b, f32x4 c) {
  return __builtin_amdgcn_mfma_f32_16x16x32_bf16(a, b, c, 0, 0, 0);
}

// ---------------- fused prologue: rope_table + x->bf16 + weight transposes ----
__global__ __launch_bounds__(256) void prep(
    const float* __restrict__ x, const float* __restrict__ W0,
    const float* __restrict__ W1, const float* __restrict__ W2,
    const float* __restrict__ W3, const float* __restrict__ W4,
    const float* __restrict__ W_out, float* __restrict__ cosT,
    float* __restrict__ sinT, unsigned short* __restrict__ xb,
    unsigned short* __restrict__ Wt, unsigned short* __restrict__ WtO) {
  __shared__ float t[64 * 65];
  int bid = blockIdx.x, tid = threadIdx.x;
  if (bid < 256) {  // rope table: S*32 = 65536 = 256*256
    int idx = bid * 256 + tid;
    int s = idx >> 5, i = idx & 31;
    double inv = pow(10000.0, -2.0 * (double)i / 64.0);
    double ang = (double)s * inv;
    cosT[idx] = (float)cos(ang);
    sinT[idx] = (float)sin(ang);
  } else if (bid < 1280) {  // fconv: x -> bf16, 1024 blocks
    int idx = ((bid - 256) * 256 + tid) * 8;
    float4 a = *(const float4*)&x[idx];
    float4 b = *(const float4*)&x[idx + 4];
    union { unsigned short us[8]; float4 f4; } u;
    u.us[0] = f2bf(a.x); u.us[1] = f2bf(a.y); u.us[2] = f2bf(a.z); u.us[3] = f2bf(a.w);
    u.us[4] = f2bf(b.x); u.us[5] = f2bf(b.y); u.us[6] = f2bf(b.z); u.us[7] = f2bf(b.w);
    *(float4*)&xb[idx] = u.f4;
  } else if (bid < 1600) {  // wtrans: 5 mats x 16 k0 x 4 n0 = 320 blocks
    int p = bid - 1280;
    int m = p / 64;
    int rem = p % 64;
    int k0 = (rem & 15) * 64;
    int n0 = (rem >> 4) * 64;
    const float* W = (m == 0) ? W0 : (m == 1) ? W1 : (m == 2) ? W2 : (m == 3) ? W3 : W4;
    int rr = tid >> 4, c4 = (tid & 15) * 4;
#pragma unroll
    for (int e = 0; e < 4; ++e) {
      int row = rr + e * 16;
      float4 v = *(const float4*)(W + (size_t)(k0 + row) * 256 + n0 + c4);
      t[(c4 + 0) * 65 + row] = v.x;
      t[(c4 + 1) * 65 + row] = v.y;
      t[(c4 + 2) * 65 + row] = v.z;
      t[(c4 + 3) * 65 + row] = v.w;
    }
    __syncthreads();
#pragma unroll
    for (int e = 0; e < 2; ++e) {
      int flat = tid + e * 256;
      int col = flat >> 3, kc = (flat & 7) * 8;
      union { unsigned short us[8]; float4 f4; } u;
#pragma unroll
      for (int i = 0; i < 8; ++i) u.us[i] = f2bf(t[col * 65 + kc + i]);
      *(float4*)(Wt + ((size_t)m * 256 + n0 + col) * 1024 + k0 + kc) = u.f4;
    }
  } else {  // wtrans_o: 16 x 16 = 256 blocks
    int p = bid - 1600;
    int k0 = (p & 15) * 64;
    int n0 = (p >> 4) * 64;
    int rr = tid >> 4, c4 = (tid & 15) * 4;
#pragma unroll
    for (int e = 0; e < 4; ++e) {
      int row = rr + e * 16;
      float4 v = *(const float4*)(W_out + (size_t)(k0 + row) * 1024 + n0 + c4);
      t[(c4 + 0) * 65 + row] = v.x;
      t[(c4 + 1) * 65 + row] = v.y;
      t[(c4 + 2) * 65 + row] = v.z;
      t[(c4 + 3) * 65 + row] = v.w;
    }
    __syncthreads();
#pragma unroll
    for (int e = 0; e < 2; ++e) {
      int flat = tid + e * 256;
      int col = flat >> 3, kc = (flat & 7) * 8;
      union { unsigned short us[8]; float4 f4; } u;
#pragma unroll
      for (int i = 0; i < 8; ++i) u.us[i] = f2bf(t[col * 65 + kc + i]);
      *(float4*)(WtO + (size_t)(n0 + col) * 1024 + k0 + kc) = u.f4;
    }
  }
}

// ---------------- fp32 GEMM body: 64x64 tile, K-step 32 (proven) --------------
__device__ __forceinline__ void gemm_body_k(const float* __restrict__ A,
                                            const float* __restrict__ B,
                                            float* __restrict__ C,
                                            int N, int K, int bm, int bn,
                                            int kS, int kE,
                                            float* As /*32*64*/, float* Bs /*32*64*/) {
  int tid = threadIdx.x;
  int tr = tid >> 4, tc = tid & 15;
  float acc[4][4] = {{0.f}};
  int arow = tid >> 2;
  int kba = (tid & 3) << 3;
  int brow = tid >> 4;
  int bcol = (tid & 15) << 2;
  const float* Ab = A + (size_t)(bm * 64) * K;
  const float* Bb = B + bn * 64;

  float4 a0 = *(const float4*)(Ab + (size_t)arow * K + kS + kba);
  float4 a1 = *(const float4*)(Ab + (size_t)arow * K + kS + kba + 4);
  float4 b0 = *(const float4*)(Bb + (size_t)(kS + brow) * N + bcol);
  float4 b1 = *(const float4*)(Bb + (size_t)(kS + brow + 16) * N + bcol);

  for (int k0 = kS; k0 < kE; k0 += 32) {
    __syncthreads();
    {
      float av[8] = {a0.x, a0.y, a0.z, a0.w, a1.x, a1.y, a1.z, a1.w};
#pragma unroll
      for (int i = 0; i < 8; ++i) {
        int k = kba + i;
        As[k * 64 + (arow ^ (((k >> 3) & 3) << 3))] = av[i];
      }
      *(float4*)&Bs[brow * 64 + bcol] = b0;
      *(float4*)&Bs[(brow + 16) * 64 + bcol] = b1;
    }
    __syncthreads();
    if (k0 + 32 < kE) {
      a0 = *(const float4*)(Ab + (size_t)arow * K + k0 + 32 + kba);
      a1 = *(const float4*)(Ab + (size_t)arow * K + k0 + 32 + kba + 4);
      b0 = *(const float4*)(Bb + (size_t)(k0 + 32 + brow) * N + bcol);
      b1 = *(const float4*)(Bb + (size_t)(k0 + 32 + brow + 16) * N + bcol);
    }
#pragma unroll
    for (int kk = 0; kk < 32; ++kk) {
      float4 a = *(const float4*)&As[kk * 64 + ((tr << 2) ^ (((kk >> 3) & 3) << 3))];
      float4 b = *(const float4*)&Bs[kk * 64 + (tc << 2)];
      acc[0][0] += a.x * b.x; acc[0][1] += a.x * b.y; acc[0][2] += a.x * b.z; acc[0][3] += a.x * b.w;
      acc[1][0] += a.y * b.x; acc[1][1] += a.y * b.y; acc[1][2] += a.y * b.z; acc[1][3] += a.y * b.w;
      acc[2][0] += a.z * b.x; acc[2][1] += a.z * b.y; acc[2][2] += a.z * b.z; acc[2][3] += a.z * b.w;
      acc[3][0] += a.w * b.x; acc[3][1] += a.w * b.y; acc[3][2] += a.w * b.z; acc[3][3] += a.w * b.w;
    }
  }
  for (int i = 0; i < 4; ++i)
    for (int jj = 0; jj < 4; ++jj)
      C[(size_t)(bm * 64 + (tr << 2) + i) * N + bn * 64 + (tc << 2) + jj] = acc[i][jj];
}

// ---------------- bf16 MFMA projection body -----------------------------------
__device__ __forceinline__ void proj_body(
    const unsigned short* __restrict__ xb, const unsigned short* __restrict__ Wt,
    const float* __restrict__ cosT, const float* __restrict__ sinT,
    unsigned short* __restrict__ Kb_s, unsigned short* __restrict__ Vt_s,
    unsigned short* __restrict__ Kb_w, unsigned short* __restrict__ Vt_w,
    unsigned short* __restrict__ Vt_c,
    int s0, int g, int mat, unsigned short* xs, unsigned short* ws) {
  int tid = threadIdx.x, w = tid >> 6, lane = tid & 63;
  int l15 = lane & 15, lg = lane >> 4;
  int rswz = (l15 & 7) << 3;
  bool isV = (mat == 1) || (mat == 3) || (mat == 4);
  const unsigned short* wt = Wt + ((size_t)mat * 256 + g * 64) * 1024;

  f32x4 acc[4];
#pragma unroll
  for (int nt = 0; nt < 4; ++nt) acc[nt] = (f32x4){0.f, 0.f, 0.f, 0.f};

  for (int k0 = 0; k0 < DIM; k0 += 64) {
#pragma unroll
    for (int e = 0; e < 2; ++e) {
      int flat = tid + e * 256;
      int row = flat >> 3, cc = flat & 7;
      int dsti = row * 64 + ((cc ^ (row & 7)) << 3);
      *(float4*)&xs[dsti] = *(const float4*)(xb + (size_t)(s0 + row) * DIM + k0 + cc * 8);
      *(float4*)&ws[dsti] = *(const float4*)(wt + (size_t)row * DIM + k0 + cc * 8);
    }
    __syncthreads();
    const unsigned short* aP = isV ? ws : xs;
    const unsigned short* bP = isV ? xs : ws;
    int arow = w * 16 + l15;
    bf16x8 af[2];
#pragma unroll
    for (int kc = 0; kc < 2; ++kc)
      af[kc] = *(const bf16x8*)&aP[(arow * 64 + kc * 32 + lg * 8) ^ rswz];
#pragma unroll
    for (int nt = 0; nt < 4; ++nt) {
      int brow = nt * 16 + l15;
      bf16x8 b0 = *(const bf16x8*)&bP[(brow * 64 + lg * 8) ^ rswz];
      bf16x8 b1 = *(const bf16x8*)&bP[(brow * 64 + 32 + lg * 8) ^ rswz];
      acc[nt] = mfma16(af[0], b0, acc[nt]);
      acc[nt] = mfma16(af[1], b1, acc[nt]);
    }
    __syncthreads();
  }

  if (!isV) {
    unsigned short* Kb = (mat == 0) ? Kb_s : Kb_w;
#pragma unroll
    for (int rr = 0; rr < 4; ++rr) {
      int tok = s0 + w * 16 + lg * 4 + rr;
#pragma unroll
      for (int p = 0; p < 2; ++p) {
        int i = p * 16 + l15;
        float c = cosT[tok * 32 + i], sn = sinT[tok * 32 + i];
        float x1 = acc[p][rr], x2 = acc[p + 2][rr];
        Kb[((size_t)g * S + tok) * 64 + i] = f2bf(x1 * c - x2 * sn);
        Kb[((size_t)g * S + tok) * 64 + i + 32] = f2bf(x2 * c + x1 * sn);
      }
    }
  } else {
    unsigned short* Vt = (mat == 1) ? Vt_s : (mat == 3) ? Vt_w : Vt_c;
#pragma unroll
    for (int rr = 0; rr < 4; ++rr) {
      int col = w * 16 + lg * 4 + rr;
#pragma unroll
      for (int nt = 0; nt < 4; ++nt) {
        int tok = s0 + nt * 16 + l15;
        Vt[((size_t)g * 64 + col) * S + tok] = f2bf(acc[nt][rr]);
      }
    }
  }
}

// ---------------- Superkernel: fp32 Q/K_cmp GEMM (VALU) + bf16 proj (MFMA) ----
__global__ __launch_bounds__(256) void qk_proj(
    const float* __restrict__ x, const float* __restrict__ W_Q,
    const float* __restrict__ W_Kc, float* __restrict__ Pq, float* __restrict__ Pk,
    const unsigned short* __restrict__ xb, const unsigned short* __restrict__ Wt,
    const float* __restrict__ cosT, const float* __restrict__ sinT,
    unsigned short* __restrict__ Kb_s, unsigned short* __restrict__ Vt_s,
    unsigned short* __restrict__ Kb_w, unsigned short* __restrict__ Vt_w,
    unsigned short* __restrict__ Vt_c) {
  __shared__ __align__(16) float lds_f[4096];
  int bid = blockIdx.x;
  int r = bid % 3;
  if (r < 2) {
    int gid = (bid / 3) * 2 + r;
    int z = gid / 640;
    int rem = gid % 640;
    int ct = rem % 20;
    int bm = rem / 20;
    int kS = z * 512, kE = kS + 512;
    float* As = lds_f;
    float* Bs = lds_f + 2048;
    if (ct < 16)
      gemm_body_k(x, W_Q, Pq + (size_t)z * S * 1024, 1024, DIM, bm, ct, kS, kE, As, Bs);
    else
      gemm_body_k(x, W_Kc, Pk + (size_t)z * S * 256, 256, DIM, bm, ct - 16, kS, kE, As, Bs);
  } else {
    int pid = bid / 3;
    int s0b = pid % 32;
    int g = (pid / 32) % 4;
    int mat = pid / 128;
    unsigned short* xs = (unsigned short*)lds_f;
    unsigned short* ws = xs + 4096;
    proj_body(xb, Wt, cosT, sinT, Kb_s, Vt_s, Kb_w, Vt_w, Vt_c, s0b * 64, g, mat,
              xs, ws);
  }
}

// ---------------- reduce split-K partials + RoPE + bf16 Q ---------------------
__global__ __launch_bounds__(256) void reduce_rope(
    const float* __restrict__ Pq, const float* __restrict__ Pk,
    const float* __restrict__ cosT, const float* __restrict__ sinT,
    float* __restrict__ Qb, unsigned short* __restrict__ Qbf,
    float* __restrict__ Kcr) {
  int idx = blockIdx.x * 256 + threadIdx.x;
  const int NQ = S * H * 32;
  if (idx < NQ) {
    int i = idx & 31;
    int rest = idx >> 5;
    int h = rest & 15;
    int s = rest >> 4;
    size_t base = (size_t)s * 1024 + h * 64 + i;
    float a1 = Pq[base] + Pq[(size_t)S * 1024 + base];
    float a2 = Pq[base + 32] + Pq[(size_t)S * 1024 + base + 32];
    float c = cosT[s * 32 + i], sn = sinT[s * 32 + i];
    float q1 = a1 * c - a2 * sn, q2 = a2 * c + a1 * sn;
    Qb[base] = q1;
    Qb[base + 32] = q2;
    Qbf[base] = f2bf(q1);
    Qbf[base + 32] = f2bf(q2);
  } else {
    int j = idx - NQ;
    if (j >= S * G * 32) return;
    int i = j & 31;
    int rest = j >> 5;
    int g = rest & 3;
    int s = rest >> 2;
    size_t base = (size_t)s * 256 + g * 64 + i;
    float a1 = Pk[base] + Pk[(size_t)S * 256 + base];
    float a2 = Pk[base + 32] + Pk[(size_t)S * 256 + base + 32];
    float c = cosT[s * 32 + i], sn = sinT[s * 32 + i];
    Kcr[base] = a1 * c - a2 * sn;
    Kcr[base + 32] = a2 * c + a1 * sn;
  }
}

// ---------------- fused pool_cmp + gating MLP ---------------------------------
__global__ __launch_bounds__(256) void post_reduce(
    const float* __restrict__ Kcr, const unsigned short* __restrict__ Vtc,
    float* __restrict__ Kc, float* __restrict__ Vc, const float* __restrict__ Q,
    const float* __restrict__ w1, const float* __restrict__ b1,
    const float* __restrict__ w2, const float* __restrict__ b2,
    float* __restrict__ gates) {
  int bid = blockIdx.x, tid = threadIdx.x;
  if (bid < 127) {
    int item = bid * 256 + tid;
    int c = item >> 8;
    int g = (item >> 6) & 3;
    int d = item & 63;
    float sk = 0.f, sv = 0.f;
    const unsigned short* vrow = Vtc + ((size_t)g * 64 + d) * S + c * 16;
    for (int l = 0; l < 32; ++l) {
      sk += Kcr[(size_t)((c * 16 + l) * G + g) * 64 + d];
      sv += bf2f(vrow[l]);
    }
    Kc[(size_t)(g * NCMP + c) * 64 + d] = sk * (1.f / 32.f);
    Vc[(size_t)(g * NCMP + c) * 64 + d] = sv * (1.f / 32.f);
  } else {
    int idx = (bid - 127) * 256 + tid;
    int s = idx >> 2, g = idx & 3;
    float qm[64];
#pragma unroll
    for (int d = 0; d < 64; ++d) {
      float a = 0.f;
      for (int hp = 0; hp < HPG; ++hp) a += Q[(size_t)(s * H + g * HPG + hp) * 64 + d];
      qm[d] = a * 0.25f;
    }
    float gl[3] = {b2[0], b2[1], b2[2]};
    for (int j = 0; j < GH; ++j) {
      float z = b1[j];
      for (int d = 0; d < 64; ++d) z += qm[d] * w1[d * GH + j];
      float sl = z / (1.f + expf(-z));
      gl[0] += sl * w2[j * 3 + 0];
      gl[1] += sl * w2[j * 3 + 1];
      gl[2] += sl * w2[j * 3 + 2];
    }
    float m = fmaxf(gl[0], fmaxf(gl[1], gl[2]));
    float e0 = expf(gl[0] - m), e1 = expf(gl[1] - m), e2 = expf(gl[2] - m);
    float inv = 1.f / (e0 + e1 + e2);
    float p0 = e0 * inv, p1 = e1 * inv, p2 = e2 * inv;
    int am = (gl[0] >= gl[1] && gl[0] >= gl[2]) ? 0 : ((gl[1] >= gl[2]) ? 1 : 2);
    float t1 = (am == 0) ? fmaxf(gl[1], gl[2])
                         : ((am == 1) ? fmaxf(gl[0], gl[2]) : fmaxf(gl[0], gl[1]));
    if (m - t1 > 50.f) {
      p0 = (am == 0) ? 1.f : 0.f;
      p1 = (am == 1) ? 1.f : 0.f;
      p2 = (am == 2) ? 1.f : 0.f;
    }
    gates[idx * 3 + 0] = p0;
    gates[idx * 3 + 1] = p1;
    gates[idx * 3 + 2] = p2;
  }
}

// ---------------- compressed attention + top-k body (fp32 exact) --------------
__device__ __forceinline__ void cmp_body(const float* __restrict__ Q,
                                         const float* __restrict__ Kc,
                                         const float* __restrict__ Vc,
                                         float* __restrict__ Ocmp,
                                         unsigned int* __restrict__ selm,
                                         int s, int g,
                                         float* q4, float* sc, float* pg) {
  int tid = threadIdx.x;
  int nvis = (s >= 31) ? (((s - 31) >> 4) + 1) : 0;
  {
    int h = tid >> 6, d = tid & 63;
    q4[h * 64 + d] = Q[(size_t)(s * H + g * HPG + h) * 64 + d];
  }
  __syncthreads();

  if (tid < 128) {
    int c = tid;
    if (c < nvis) {
      float a0 = 0.f, a1 = 0.f, a2 = 0.f, a3 = 0.f;
      const float* kr = &Kc[(size_t)(g * NCMP + c) * 64];
#pragma unroll 4
      for (int kk = 0; kk < 16; ++kk) {
        float4 kv = *(const float4*)&kr[kk * 4];
        float4 q0 = *(const float4*)&q4[0 * 64 + kk * 4];
        float4 q1 = *(const float4*)&q4[1 * 64 + kk * 4];
        float4 q2 = *(const float4*)&q4[2 * 64 + kk * 4];
        float4 q3 = *(const float4*)&q4[3 * 64 + kk * 4];
        a0 += q0.x * kv.x + q0.y * kv.y + q0.z * kv.z + q0.w * kv.w;
        a1 += q1.x * kv.x + q1.y * kv.y + q1.z * kv.z + q1.w * kv.w;
        a2 += q2.x * kv.x + q2.y * kv.y + q2.z * kv.z + q2.w * kv.w;
        a3 += q3.x * kv.x + q3.y * kv.y + q3.z * kv.z + q3.w * kv.w;
      }
      sc[0 * 128 + c] = a0 * 0.125f;
      sc[1 * 128 + c] = a1 * 0.125f;
      sc[2 * 128 + c] = a2 * 0.125f;
      sc[3 * 128 + c] = a3 * 0.125f;
    } else {
      sc[0 * 128 + c] = -INFINITY;
      sc[1 * 128 + c] = -INFINITY;
      sc[2 * 128 + c] = -INFINITY;
      sc[3 * 128 + c] = -INFINITY;
    }
  }
  __syncthreads();

  int w = tid >> 6, lane = tid & 63;
  {
    float v0 = sc[w * 128 + lane];
    float v1 = (lane + 64 < NCMP) ? sc[w * 128 + lane + 64] : -INFINITY;
    float m = fmaxf(v0, v1);
    for (int off = 32; off; off >>= 1) m = fmaxf(m, __shfl_xor(m, off));
    float e0 = (m > -INFINITY && v0 > -INFINITY) ? expf(v0 - m) : 0.f;
    float e1 = (m > -INFINITY && v1 > -INFINITY) ? expf(v1 - m) : 0.f;
    float sum = e0 + e1;
    for (int off = 32; off; off >>= 1) sum += __shfl_xor(sum, off);
    float inv = (sum > 0.f) ? 1.f / sum : 0.f;
    sc[w * 128 + lane] = e0 * inv;
    if (lane + 64 < NCMP) sc[w * 128 + lane + 64] = e1 * inv;
    if (lane == 63) sc[w * 128 + 127] = 0.f;
  }
  __syncthreads();

  {
    int h = tid >> 6, d = tid & 63;
    float o = 0.f;
#pragma unroll 4
    for (int c = 0; c < nvis; ++c)
      o += sc[h * 128 + c] * Vc[(size_t)(g * NCMP + c) * 64 + d];
    Ocmp[(size_t)(s * H + g * HPG + h) * 64 + d] = o;
  }

  if (tid < JBLK) {
    int j = tid;
    float a = 0.f;
#pragma unroll
    for (int h = 0; h < 4; ++h) {
      const float* row = &sc[h * 128];
      float v = row[4 * j] + row[4 * j + 1] + row[4 * j + 2] + 0.5f * row[4 * j + 3];
      if (j > 0) v += 0.5f * row[4 * j - 1];
      a += v;
    }
    pg[j] = a;
  }
  __syncthreads();

  if (tid < 64) {
    int j = tid & 31;
    int cur = s >> 6;
    float v = (j * 64 <= s) ? pg[j] : -1e30f;
    if (j == 0 || j == cur) v = 1e9f;
    unsigned int mask = 0;
#pragma unroll 1
    for (int n = 0; n < NSEL; ++n) {
      float bv = v;
      int bj = j;
#pragma unroll
      for (int off = 1; off < 32; off <<= 1) {
        float ov = __shfl_xor(bv, off);
        int oj = __shfl_xor(bj, off);
        if (ov > bv || (ov == bv && oj < bj)) { bv = ov; bj = oj; }
      }
      mask |= 1u << bj;
      if (j == bj) v = -INFINITY;
    }
    if (tid == 0) selm[(size_t)s * G + g] = mask;
  }
}

__global__ __launch_bounds__(256) void cmp_attn(const float* __restrict__ Qb,
                                                const float* __restrict__ Kc,
                                                const float* __restrict__ Vc,
                                                float* __restrict__ Ocmp,
                                                unsigned int* __restrict__ selm) {
  __shared__ float q4[256];
  __shared__ float sc[512];
  __shared__ float pg[JBLK];
  cmp_body(Qb, Kc, Vc, Ocmp, selm, blockIdx.x, blockIdx.y, q4, sc, pg);
}

// ---------------- MFMA flash attention body: MODE 0 sel / 1 win ---------------
template <int MODE>
__device__ __forceinline__ void attn_body(
    const unsigned short* __restrict__ Qbf, const unsigned short* __restrict__ Kb,
    const unsigned short* __restrict__ Vtb, const unsigned int* __restrict__ selm,
    float* __restrict__ O, int t0, int g,
    unsigned short* Kl, unsigned short* Vt, unsigned short* Pl,
    unsigned int* sel_l, int* blist, int* nB_p) {
  int tid = threadIdx.x;
  int w = tid >> 6, lane = tid & 63;
  int l15 = lane & 15, lg = lane >> 4;
  int rswz = (l15 & 7) << 3;
  int jdiag = t0 >> 6;

  if (MODE == 0 && tid < 16) sel_l[tid] = selm[(t0 + tid) * G + g];
  __syncthreads();
  if (tid == 0) {
    int n = 0;
    if (MODE == 0) {
      unsigned int un = 0;
      for (int i = 0; i < 16; ++i) un |= sel_l[i];
      for (int j = 0; j <= jdiag; ++j)
        if ((un >> j) & 1u) blist[n++] = j;
    } else {
      int lo = t0 - (WWIN - 1);
      int j0 = (lo > 0) ? (lo >> 6) : 0;
      for (int j = j0; j <= jdiag; ++j) blist[n++] = j;
    }
    *nB_p = n;
  }
  __syncthreads();
  int nB = *nB_p;

  int tok = t0 + l15;
  bf16x8 qf[2];
  {
    const unsigned short* qb = Qbf + ((size_t)tok * H + g * HPG + w) * 64;
    qf[0] = *(const bf16x8*)(qb + lg * 8);
    qf[1] = *(const bf16x8*)(qb + 32 + lg * 8);
  }

  float mrun = -INFINITY, lrun = 0.f;
  f32x4 oacc[4];
#pragma unroll
  for (int dt = 0; dt < 4; ++dt) oacc[dt] = (f32x4){0.f, 0.f, 0.f, 0.f};

  for (int b = 0; b < nB; ++b) {
    int j = blist[b];
    int ku = j * 64;

    {
      const unsigned short* src = Kb + ((size_t)g * S + ku) * 64;
#pragma unroll
      for (int c2 = 0; c2 < 2; ++c2) {
        int chunk = tid + c2 * 256;
        int key = chunk >> 3, cc = chunk & 7;
        *(float4*)&Kl[key * 64 + ((cc ^ (key & 7)) << 3)] =
            *(const float4*)(src + chunk * 8);
      }
#pragma unroll
      for (int c2 = 0; c2 < 2; ++c2) {
        int chunk = tid + c2 * 256;
        int dim = chunk >> 3, cc = chunk & 7;
        *(float4*)&Vt[dim * 64 + ((cc ^ (dim & 7)) << 3)] =
            *(const float4*)(Vtb + ((size_t)g * 64 + dim) * S + ku + cc * 8);
      }
    }
    __syncthreads();

    f32x4 sf[4];
#pragma unroll
    for (int kt = 0; kt < 4; ++kt) sf[kt] = (f32x4){0.f, 0.f, 0.f, 0.f};
#pragma unroll
    for (int kt = 0; kt < 4; ++kt) {
      int krow = kt * 16 + l15;
      bf16x8 kf0 = *(const bf16x8*)&Kl[(krow * 64 + lg * 8) ^ rswz];
      bf16x8 kf1 = *(const bf16x8*)&Kl[(krow * 64 + 32 + lg * 8) ^ rswz];
      sf[kt] = mfma16(kf0, qf[0], sf[kt]);
      sf[kt] = mfma16(kf1, qf[1], sf[kt]);
    }

    bool bsel = true;
    if (MODE == 0) bsel = ((sel_l[l15] >> j) & 1u) != 0;
    float sv2[4][4];
    if (j == jdiag) {
#pragma unroll
      for (int kt = 0; kt < 4; ++kt)
#pragma unroll
        for (int rr = 0; rr < 4; ++rr) {
          int u = ku + kt * 16 + lg * 4 + rr;
          sv2[kt][rr] = (u <= tok) ? sf[kt][rr] * SCL2 : -INFINITY;
        }
    } else if (MODE == 1 && (ku + WWIN <= t0 + 15)) {
#pragma unroll
      for (int kt = 0; kt < 4; ++kt)
#pragma unroll
        for (int rr = 0; rr < 4; ++rr) {
          int u = ku + kt * 16 + lg * 4 + rr;
          sv2[kt][rr] = (u + WWIN > tok) ? sf[kt][rr] * SCL2 : -INFINITY;
        }
    } else {
#pragma unroll
      for (int kt = 0; kt < 4; ++kt)
#pragma unroll
        for (int rr = 0; rr < 4; ++rr) sv2[kt][rr] = sf[kt][rr] * SCL2;
    }

    float pmax = -INFINITY;
#pragma unroll
    for (int kt = 0; kt < 4; ++kt)
#pragma unroll
      for (int rr = 0; rr < 4; ++rr) pmax = fmaxf(pmax, sv2[kt][rr]);
    pmax = fmaxf(pmax, __shfl_xor(pmax, 16));
    pmax = fmaxf(pmax, __shfl_xor(pmax, 32));
    if (MODE == 0 && !bsel) pmax = -INFINITY;

    if (__any(pmax > mrun)) {
      float mnew = fmaxf(mrun, pmax);
      float mc = (mnew == -INFINITY) ? 0.f : mnew;
      float fac = exp2f(mrun - mc);
      mrun = mnew;
      lrun *= fac;
#pragma unroll
      for (int dt = 0; dt < 4; ++dt)
#pragma unroll
        for (int rr = 0; rr < 4; ++rr) oacc[dt][rr] *= fac;
    }
    float mcb = (MODE == 0 && !bsel) ? INFINITY
                                     : ((mrun == -INFINITY) ? 0.f : mrun);

    float psum = 0.f;
    unsigned short pb[16];
#pragma unroll
    for (int kt = 0; kt < 4; ++kt)
#pragma unroll
      for (int rr = 0; rr < 4; ++rr) {
        float e = exp2f(sv2[kt][rr] - mcb);
        psum += e;
        pb[kt * 4 + rr] = f2bf_hw(e);
      }
    psum += __shfl_xor(psum, 16);
    psum += __shfl_xor(psum, 32);
    lrun += psum;

    {
      unsigned short* pw = Pl + w * 1024;
#pragma unroll
      for (int kt = 0; kt < 4; ++kt) {
        int idx = (l15 * 64 + kt * 16 + lg * 4) ^ rswz;
        unsigned int lo = (unsigned)pb[kt * 4] | ((unsigned)pb[kt * 4 + 1] << 16);
        unsigned int hi = (unsigned)pb[kt * 4 + 2] | ((unsigned)pb[kt * 4 + 3] << 16);
        *(uint2*)&pw[idx] = make_uint2(lo, hi);
      }
    }

#pragma unroll
    for (int kc = 0; kc < 2; ++kc) {
      bf16x8 pf = *(const bf16x8*)&Pl[w * 1024 + ((l15 * 64 + kc * 32 + lg * 8) ^ rswz)];
#pragma unroll
      for (int dt = 0; dt < 4; ++dt) {
        bf16x8 vf = *(const bf16x8*)&Vt[((dt * 16 + l15) * 64 + kc * 32 + lg * 8) ^ rswz];
        oacc[dt] = mfma16(vf, pf, oacc[dt]);
      }
    }
    __syncthreads();
  }

  {
    float inv = (lrun > 0.f) ? 1.f / lrun : 0.f;
    float* ob = O + ((size_t)tok * H + g * HPG + w) * 64;
#pragma unroll
    for (int dt = 0; dt < 4; ++dt) {
      float4 v;
      v.x = oacc[dt][0] * inv;
      v.y = oacc[dt][1] * inv;
      v.z = oacc[dt][2] * inv;
      v.w = oacc[dt][3] * inv;
      *(float4*)(ob + dt * 16 + lg * 4) = v;
    }
  }
}

// ---------------- sel (z=0) / win (z=1) attention in one dispatch -------------
__global__ __launch_bounds__(256) void attn_fused(
    const unsigned short* __restrict__ Qbf,
    const unsigned short* __restrict__ Kbs, const unsigned short* __restrict__ Vts,
    const unsigned short* __restrict__ Kbw, const unsigned short* __restrict__ Vtw,
    const unsigned int* __restrict__ selm,
    float* __restrict__ Osel, float* __restrict__ Owin) {
  __shared__ unsigned short Kl[4096];
  __shared__ unsigned short Vt[4096];
  __shared__ unsigned short Pl[4096];
  __shared__ unsigned int sel_l[16];
  __shared__ int blist[JBLK];
  __shared__ int nB_s;
  int t0 = blockIdx.x * 16;
  int g = blockIdx.y;
  if (blockIdx.z == 0)
    attn_body<0>(Qbf, Kbs, Vts, selm, Osel, t0, g, Kl, Vt, Pl, sel_l, blist, &nB_s);
  else
    attn_body<1>(Qbf, Kbw, Vtw, nullptr, Owin, t0, g, Kl, Vt, Pl, sel_l, blist,
                 &nB_s);
}

// ---------------- combine branches -> bf16 ------------------------------------
__global__ void combine(const float* __restrict__ Oc, const float* __restrict__ Os,
                        const float* __restrict__ Ow, const float* __restrict__ gates,
                        unsigned short* __restrict__ Ob) {
  int idx = blockIdx.x * blockDim.x + threadIdx.x;
  if (idx >= S * H * DV) return;
  int h = (idx >> 6) & 15;
  int s = idx >> 10;
  int g = h >> 2;
  const float* gp = &gates[(size_t)(s * G + g) * 3];
  Ob[idx] = f2bf(gp[0] * Oc[idx] + gp[1] * Os[idx] + gp[2] * Ow[idx]);
}

// ---------------- bf16 MFMA out projection ------------------------------------
__global__ __launch_bounds__(256) void gemm_out(const unsigned short* __restrict__ Ob,
                                                const unsigned short* __restrict__ Wt,
                                                float* __restrict__ out) {
  __shared__ unsigned short xs[64 * 64];
  __shared__ unsigned short ws[64 * 64];
  int s0 = blockIdx.x * 64;
  int n0 = blockIdx.y * 64;
  int tid = threadIdx.x, w = tid >> 6, lane = tid & 63;
  int l15 = lane & 15, lg = lane >> 4;
  int rswz = (l15 & 7) << 3;

  f32x4 acc[4];
#pragma unroll
  for (int nt = 0; nt < 4; ++nt) acc[nt] = (f32x4){0.f, 0.f, 0.f, 0.f};

  for (int k0 = 0; k0 < DIM; k0 += 64) {
#pragma unroll
    for (int e = 0; e < 2; ++e) {
      int flat = tid + e * 256;
      int row = flat >> 3, cc = flat & 7;
      int dsti = row * 64 + ((cc ^ (row & 7)) << 3);
      *(float4*)&xs[dsti] = *(const float4*)(Ob + (size_t)(s0 + row) * DIM + k0 + cc * 8);
      *(float4*)&ws[dsti] = *(const float4*)(Wt + (size_t)(n0 + row) * DIM + k0 + cc * 8);
    }
    __syncthreads();
    int arow = w * 16 + l15;
    bf16x8 af0 = *(const bf16x8*)&xs[(arow * 64 + lg * 8) ^ rswz];
    bf16x8 af1 = *(const bf16x8*)&xs[(arow * 64 + 32 + lg * 8) ^ rswz];
#pragma unroll
    for (int nt = 0; nt < 4; ++nt) {
      int brow = nt * 16 + l15;
      bf16x8 b0 = *(const bf16x8*)&ws[(brow * 64 + lg * 8) ^ rswz];
      bf16x8 b1 = *(const bf16x8*)&ws[(brow * 64 + 32 + lg * 8) ^ rswz];
      acc[nt] = mfma16(af0, b0, acc[nt]);
      acc[nt] = mfma16(af1, b1, acc[nt]);
    }
    __syncthreads();
  }

#pragma unroll
  for (int nt = 0; nt < 4; ++nt)
#pragma unroll
    for (int rr = 0; rr < 4; ++rr)
      out[(size_t)(s0 + w * 16 + lg * 4 + rr) * 1024 + n0 + nt * 16 + l15] =
          acc[nt][rr];
}

// ---------------- host launch ---------------------------------------------------
extern "C" void kernel_launch(void* const* d_in, const int* in_sizes, int n_in,
                              void* d_out, int out_size, void* d_ws, size_t ws_size,
                              hipStream_t stream) {
  const float* x = (const float*)d_in[0];
  const float* W_Q = (const float*)d_in[1];
  const float* W_K_sel = (const float*)d_in[2];
  const float* W_V_sel = (const float*)d_in[3];
  const float* W_K_win = (const float*)d_in[4];
  const float* W_V_win = (const float*)d_in[5];
  const float* W_K_cmp = (const float*)d_in[6];
  const float* W_V_cmp = (const float*)d_in[7];
  const float* W_out = (const float*)d_in[8];
  const float* gw1 = (const float*)d_in[9];
  const float* gb1 = (const float*)d_in[10];
  const float* gw2 = (const float*)d_in[11];
  const float* gb2 = (const float*)d_in[12];

  float* w = (float*)d_ws;
  float* cosT = w;  w += S * 32;
  float* sinT = w;  w += S * 32;
  float* Qb   = w;  w += S * H * DK;
  float* Kcr  = w;  w += S * G * DK;
  float* Kc   = w;  w += G * NCMP * DK;
  float* Vc   = w;  w += G * NCMP * DV;
  float* Ocmp = w;  w += S * H * DV;   // aliased by Pq (dead until cmp_attn)
  float* Osel = w;  w += S * H * DV;   // aliased by Pq tail
  float* Owin = w;  w += S * H * DV;   // aliased by Pk
  float* gates= w;  w += S * G * 3;
  unsigned int* selm = (unsigned int*)w;  w += S * G;
  unsigned short* Kbf_s = (unsigned short*)w;  w += (size_t)G * S * 64 / 2;
  unsigned short* Kbf_w = (unsigned short*)w;  w += (size_t)G * S * 64 / 2;
  unsigned short* Vt_s  = (unsigned short*)w;  w += (size_t)G * S * 64 / 2;
  unsigned short* Vt_w  = (unsigned short*)w;  w += (size_t)G * S * 64 / 2;
  unsigned short* Vt_c  = (unsigned short*)w;  w += (size_t)G * S * 64 / 2;
  unsigned short* Qbf   = (unsigned short*)w;  w += (size_t)S * H * 64 / 2;
  unsigned short* xb    = (unsigned short*)w;  w += (size_t)S * DIM / 2;
  unsigned short* Wt    = (unsigned short*)w;  w += (size_t)5 * 256 * DIM / 2;
  unsigned short* Ob    = (unsigned short*)w;  w += (size_t)S * H * DV / 2;
  unsigned short* WtO   = (unsigned short*)w;  w += (size_t)DIM * DIM / 2;

  // split-K partials alias the (not-yet-written) attention output buffers:
  float* Pq = Ocmp;
  float* Pk = Owin;

  prep<<<1856, 256, 0, stream>>>(x, W_K_sel, W_V_sel, W_K_win, W_V_win, W_V_cmp,
                                 W_out, cosT, sinT, xb, Wt, WtO);

  qk_proj<<<1920, 256, 0, stream>>>(x, W_Q, W_K_cmp, Pq, Pk, xb, Wt, cosT, sinT,
                                    Kbf_s, Vt_s, Kbf_w, Vt_w, Vt_c);
  reduce_rope<<<(S * (H + G) * 32 + 255) / 256, 256, 0, stream>>>(
      Pq, Pk, cosT, sinT, Qb, Qbf, Kcr);

  post_reduce<<<159, 256, 0, stream>>>(Kcr, Vt_c, Kc, Vc, Qb, gw1, gb1, gw2, gb2,
                                       gates);

  cmp_attn<<<dim3(S, G), 256, 0, stream>>>(Qb, Kc, Vc, Ocmp, selm);
  attn_fused<<<dim3(S / 16, G, 2), 256, 0, stream>>>(Qbf, Kbf_s, Vt_s, Kbf_w, Vt_w,
                                                     selm, Osel, Owin);

  combine<<<(S * H * DV + 255) / 256, 256, 0, stream>>>(Ocmp, Osel, Owin, gates, Ob);

  gemm_out<<<dim3(S / 64, DIM / 64), 256, 0, stream>>>(Ob, WtO, (float*)d_out);
}